// Round 7
// baseline (382.285 us; speedup 1.0000x reference)
//
#include <hip/hip_runtime.h>

#define HDIM 96

__global__ void zero_k(int* __restrict__ p, int n) {
  int i = blockIdx.x * blockDim.x + threadIdx.x;
  if (i < n) p[i] = 0;
}

// count in-degree AND record each edge's arrival rank at its dst
__global__ void deg_rank_k(const int* __restrict__ dst, int* __restrict__ indeg,
                           int* __restrict__ rank, int e) {
  int i = blockIdx.x * blockDim.x + threadIdx.x;
  if (i < e) rank[i] = atomicAdd(&indeg[dst[i]], 1);
}

__device__ __forceinline__ int wave_incl_scan(int v, int lane) {
#pragma unroll
  for (int off = 1; off < 64; off <<= 1) {
    int t = __shfl_up(v, off, 64);
    if (lane >= off) v += t;
  }
  return v;
}

// Phase A: bsum[b] = sum of indeg[b*1024 .. b*1024+1024)
__global__ __launch_bounds__(1024) void scan_a_k(const int* __restrict__ indeg,
                                                 int* __restrict__ bsum, int n) {
  const int tid = threadIdx.x;
  const int i = blockIdx.x * 1024 + tid;
  int v = (i < n) ? indeg[i] : 0;
#pragma unroll
  for (int off = 32; off; off >>= 1) v += __shfl_down(v, off, 64);
  __shared__ int ws[16];
  if ((tid & 63) == 0) ws[tid >> 6] = v;
  __syncthreads();
  if (tid < 16) {
    int s = ws[tid];
#pragma unroll
    for (int off = 8; off; off >>= 1) s += __shfl_down(s, off, 16);
    if (tid == 0) bsum[blockIdx.x] = s;
  }
}

// Phase B: exclusive scan of bsum[0..nb) -> bbase; offsets[n] = grand total. nb <= 1024.
__global__ __launch_bounds__(1024) void scan_b_k(const int* __restrict__ bsum,
                                                 int* __restrict__ bbase,
                                                 int* __restrict__ offsets, int nb, int n) {
  __shared__ int ws[16];
  const int tid = threadIdx.x, lane = tid & 63, w = tid >> 6;
  const int v = (tid < nb) ? bsum[tid] : 0;
  int incl = wave_incl_scan(v, lane);
  if (lane == 63) ws[w] = incl;
  __syncthreads();
  if (tid < 16) {
    int s = ws[tid];
#pragma unroll
    for (int off = 1; off < 16; off <<= 1) {
      int t = __shfl_up(s, off, 16);
      if (tid >= off) s += t;
    }
    ws[tid] = s;
  }
  __syncthreads();
  incl += (w > 0 ? ws[w - 1] : 0);
  if (tid < nb) bbase[tid] = incl - v;
  if (tid == 0) offsets[n] = ws[15];
}

// Phase C: per-chunk rescan + base add; also dis = rsqrt(1+indeg)
__global__ __launch_bounds__(1024) void scan_c_k(const int* __restrict__ indeg,
                                                 const int* __restrict__ bbase,
                                                 int* __restrict__ offsets,
                                                 float* __restrict__ dis, int n) {
  __shared__ int ws[16];
  const int tid = threadIdx.x, lane = tid & 63, w = tid >> 6;
  const int i = blockIdx.x * 1024 + tid;
  const int v = (i < n) ? indeg[i] : 0;
  int incl = wave_incl_scan(v, lane);
  if (lane == 63) ws[w] = incl;
  __syncthreads();
  if (tid < 16) {
    int s = ws[tid];
#pragma unroll
    for (int off = 1; off < 16; off <<= 1) {
      int t = __shfl_up(s, off, 16);
      if (tid >= off) s += t;
    }
    ws[tid] = s;
  }
  __syncthreads();
  incl += (w > 0 ? ws[w - 1] : 0);
  if (i < n) {
    offsets[i] = bbase[blockIdx.x] + incl - v;
    dis[i] = rsqrtf((float)(1 + v));
  }
}

// atomic-free slot calc; fire-and-forget atomicExch avoids partial-line store amplification
__global__ void place_k(const int* __restrict__ src, const int* __restrict__ dst,
                        const int* __restrict__ rank, const int* __restrict__ offsets,
                        int* __restrict__ csr_src, int e) {
  int i = blockIdx.x * blockDim.x + threadIdx.x;
  if (i >= e) return;
  int d = dst[i];
  atomicExch(&csr_src[offsets[d] + rank[i]], src[i]);
}

// o[i,:] = dis[i] * x[i,:]
__global__ void scale_k(const float* __restrict__ x, const float* __restrict__ dis,
                        float* __restrict__ o, int n) {
  int t = blockIdx.x * blockDim.x + threadIdx.x;
  if (t >= n * 24) return;
  const float d = dis[t / 24];
  float4 v = ((const float4*)x)[t];
  v.x *= d; v.y *= d; v.z *= d; v.w *= d;
  ((float4*)o)[t] = v;
}

// agg[d,:] = dis[d] * ( hp[d,:] + sum_{s->d} hp[s,:] )   (hp is pre-scaled dis*h)
__global__ __launch_bounds__(192) void gather_k(
    const int* __restrict__ csr_src, const int* __restrict__ offsets,
    const float* __restrict__ dis, const float* __restrict__ hp,
    float* __restrict__ agg, int n) {
  const int tid  = threadIdx.x;
  const int node = blockIdx.x * 8 + tid / 24;
  const int q    = tid % 24;
  if (node >= n) return;
  float4 acc = ((const float4*)(hp + (size_t)node * HDIM))[q];   // self term
  int i = offsets[node];
  const int end = offsets[node + 1];
  for (; i + 3 < end; i += 4) {
    const int s0 = csr_src[i], s1 = csr_src[i + 1], s2 = csr_src[i + 2], s3 = csr_src[i + 3];
    const float4 v0 = ((const float4*)(hp + (size_t)s0 * HDIM))[q];
    const float4 v1 = ((const float4*)(hp + (size_t)s1 * HDIM))[q];
    const float4 v2 = ((const float4*)(hp + (size_t)s2 * HDIM))[q];
    const float4 v3 = ((const float4*)(hp + (size_t)s3 * HDIM))[q];
    acc.x += v0.x + v1.x + v2.x + v3.x;
    acc.y += v0.y + v1.y + v2.y + v3.y;
    acc.z += v0.z + v1.z + v2.z + v3.z;
    acc.w += v0.w + v1.w + v2.w + v3.w;
  }
  for (; i < end; i++) {
    const int s0 = csr_src[i];
    const float4 v0 = ((const float4*)(hp + (size_t)s0 * HDIM))[q];
    acc.x += v0.x; acc.y += v0.y; acc.z += v0.z; acc.w += v0.w;
  }
  const float dd = dis[node];
  acc.x *= dd; acc.y *= dd; acc.z *= dd; acc.w *= dd;
  ((float4*)(agg + (size_t)node * HDIM))[q] = acc;
}

// ---- occupancy-first fp32 GEMM ----
// out[n,96] = [A0|A1][n, 96*nkt] @ W[96*nkt, 96] + bias.
// 64-row x 96-col tile, 384 threads (6 waves) -> 782 blocks, ~57% occupancy.
// Per-thread 4x4 micro-tile. A staged transposed in LDS (26 KB, conflict-free
// writes, b128 broadcast reads); W + bias read from global (L1/L2-resident).
// DUAL: second weight set reuses the staged A tile; out1 scaled by dis[row]
// (pre-scaled message for the next hop). nkt=2 -> concat GEMM (A0 then A1).
template<bool RELU, bool DUAL>
__global__ __launch_bounds__(384, 2) void gemm_k(
    const float* __restrict__ A0, const float* __restrict__ A1,
    const float* __restrict__ W0, const float* __restrict__ b0, float* __restrict__ out0,
    const float* __restrict__ W1, const float* __restrict__ b1, float* __restrict__ out1,
    const float* __restrict__ dis, int n, int nkt) {
  __shared__ float AsT[96 * 68];           // 26.1 KB
  const int t  = threadIdx.x;
  const int cg = t % 24;                   // cols [4cg, 4cg+4)
  const int rg = t / 24;                   // rows [4rg, 4rg+4), 16 row-groups
  const int row0 = blockIdx.x * 64;

  float acc0[4][4], acc1[4][4];
  {
    const float4 b = *(const float4*)(b0 + cg * 4);
#pragma unroll
    for (int j = 0; j < 4; j++) { acc0[j][0]=b.x; acc0[j][1]=b.y; acc0[j][2]=b.z; acc0[j][3]=b.w; }
    if (DUAL) {
      const float4 c = *(const float4*)(b1 + cg * 4);
#pragma unroll
      for (int j = 0; j < 4; j++) { acc1[j][0]=c.x; acc1[j][1]=c.y; acc1[j][2]=c.z; acc1[j][3]=c.w; }
    }
  }

  for (int kt = 0; kt < nkt; kt++) {
    const float* A = (kt == 0) ? A0 : A1;
    const float* Wp0 = W0 + (size_t)kt * HDIM * HDIM;
    const float* Wp1 = DUAL ? (W1 + (size_t)kt * HDIM * HDIM) : nullptr;
    __syncthreads();
    // stage 64x96 A tile transposed: lanes walk r fastest -> conflict-free LDS writes
    for (int idx = t; idx < 1536; idx += 384) {
      const int q = idx >> 6, r = idx & 63;
      float4 v = make_float4(0.f, 0.f, 0.f, 0.f);
      if (row0 + r < n) v = *(const float4*)(A + (size_t)(row0 + r) * HDIM + 4 * q);
      AsT[(4 * q + 0) * 68 + r] = v.x;
      AsT[(4 * q + 1) * 68 + r] = v.y;
      AsT[(4 * q + 2) * 68 + r] = v.z;
      AsT[(4 * q + 3) * 68 + r] = v.w;
    }
    __syncthreads();
#pragma unroll 4
    for (int k = 0; k < HDIM; k++) {
      const float4 a = *(const float4*)(&AsT[k * 68 + rg * 4]);
      const float av[4] = {a.x, a.y, a.z, a.w};
      const float4 w = *(const float4*)(Wp0 + (size_t)k * HDIM + cg * 4);
      const float wv[4] = {w.x, w.y, w.z, w.w};
#pragma unroll
      for (int j = 0; j < 4; j++)
#pragma unroll
        for (int c = 0; c < 4; c++)
          acc0[j][c] = fmaf(av[j], wv[c], acc0[j][c]);
      if (DUAL) {
        const float4 u = *(const float4*)(Wp1 + (size_t)k * HDIM + cg * 4);
        const float uv[4] = {u.x, u.y, u.z, u.w};
#pragma unroll
        for (int j = 0; j < 4; j++)
#pragma unroll
          for (int c = 0; c < 4; c++)
            acc1[j][c] = fmaf(av[j], uv[c], acc1[j][c]);
      }
    }
  }

#pragma unroll
  for (int j = 0; j < 4; j++) {
    const int r = row0 + rg * 4 + j;
    if (r < n) {
      float4 o;
      o.x = RELU ? fmaxf(acc0[j][0], 0.f) : acc0[j][0];
      o.y = RELU ? fmaxf(acc0[j][1], 0.f) : acc0[j][1];
      o.z = RELU ? fmaxf(acc0[j][2], 0.f) : acc0[j][2];
      o.w = RELU ? fmaxf(acc0[j][3], 0.f) : acc0[j][3];
      *(float4*)(out0 + (size_t)r * HDIM + cg * 4) = o;
      if (DUAL) {
        const float d = dis[r];
        float4 p;
        p.x = d * fmaxf(acc1[j][0], 0.f);
        p.y = d * fmaxf(acc1[j][1], 0.f);
        p.z = d * fmaxf(acc1[j][2], 0.f);
        p.w = d * fmaxf(acc1[j][3], 0.f);
        *(float4*)(out1 + (size_t)r * HDIM + cg * 4) = p;
      }
    }
  }
}

extern "C" void kernel_launch(void* const* d_in, const int* in_sizes, int n_in,
                              void* d_out, int out_size, void* d_ws, size_t ws_size,
                              hipStream_t stream) {
  const float* x       = (const float*)d_in[0];
  const int*   edge    = (const int*)d_in[1];
  const float* W_local = (const float*)d_in[2];
  const float* b_local = (const float*)d_in[3];
  const float* W_g1    = (const float*)d_in[4];
  const float* b_g1    = (const float*)d_in[5];
  const float* W_g2    = (const float*)d_in[6];
  const float* b_g2    = (const float*)d_in[7];
  const float* W_fuse  = (const float*)d_in[8]; // [192, 96] row-major
  const float* b_fuse  = (const float*)d_in[9];
  float* out = (float*)d_out;

  const int n = in_sizes[0] / HDIM;
  const int e = in_sizes[1] / 2;
  const int* src = edge;
  const int* dst = edge + e;
  const int nb = (n + 1023) / 1024;

  char* ws = (char*)d_ws;
  auto alloc = [&](size_t bytes) { char* p = ws; ws += (bytes + 255) & ~(size_t)255; return p; };
  int*   indeg   = (int*)alloc((size_t)n * 4);
  float* dis     = (float*)alloc((size_t)n * 4);
  int*   offsets = (int*)alloc((size_t)(n + 1) * 4);
  int*   bsum    = (int*)alloc((size_t)nb * 4);
  int*   bbase   = (int*)alloc((size_t)nb * 4);
  int*   rank    = (int*)alloc((size_t)e * 4);
  int*   csr_src = (int*)alloc((size_t)e * 4);
  float* bufA    = (float*)alloc((size_t)n * HDIM * 4);   // ax / ag2
  float* bufB    = (float*)alloc((size_t)n * HDIM * 4);   // x' then local
  float* bufC    = (float*)alloc((size_t)n * HDIM * 4);   // g1' then g2

  zero_k<<<(n + 255) / 256, 256, 0, stream>>>(indeg, n);
  deg_rank_k<<<(e + 255) / 256, 256, 0, stream>>>(dst, indeg, rank, e);
  scan_a_k<<<nb, 1024, 0, stream>>>(indeg, bsum, n);
  scan_b_k<<<1, 1024, 0, stream>>>(bsum, bbase, offsets, nb, n);
  scan_c_k<<<nb, 1024, 0, stream>>>(indeg, bbase, offsets, dis, n);
  place_k<<<(e + 255) / 256, 256, 0, stream>>>(src, dst, rank, offsets, csr_src, e);

  const int ggrid = (n + 7) / 8;
  const int gb = (n + 63) / 64;

  // x' = dis·x  (bufB is free until the dual GEMM overwrites it)
  scale_k<<<(n * 24 + 255) / 256, 256, 0, stream>>>(x, dis, bufB, n);
  // ax = dis·(x'[d] + Σ x'[s])
  gather_k<<<ggrid, 192, 0, stream>>>(csr_src, offsets, dis, bufB, bufA, n);
  // local = relu(ax@W_local+b);  g1' = dis·relu(ax@W_g1+b)   (one A pass)
  gemm_k<true, true><<<gb, 384, 0, stream>>>(bufA, nullptr, W_local, b_local, bufB,
                                             W_g1, b_g1, bufC, dis, n, 1);
  // ag2 = dis·(g1'[d] + Σ g1'[s]);  g2 = relu(ag2@W_g2+b)
  gather_k<<<ggrid, 192, 0, stream>>>(csr_src, offsets, dis, bufC, bufA, n);
  gemm_k<true, false><<<gb, 384, 0, stream>>>(bufA, nullptr, W_g2, b_g2, bufC,
                                              nullptr, nullptr, nullptr, nullptr, n, 1);
  // out = [local | g2] @ W_fuse + b_fuse   (K=192: two 96-tiles)
  gemm_k<false, false><<<gb, 384, 0, stream>>>(bufB, bufC, W_fuse, b_fuse, out,
                                               nullptr, nullptr, nullptr, nullptr, n, 2);
}

// Round 8
// 348.745 us; speedup vs baseline: 1.0962x; 1.0962x over previous
//
#include <hip/hip_runtime.h>

#define HDIM 96

__global__ void zero_k(int* __restrict__ p, int n) {
  int i = blockIdx.x * blockDim.x + threadIdx.x;
  if (i < n) p[i] = 0;
}

// count in-degree AND record each edge's arrival rank at its dst
__global__ void deg_rank_k(const int* __restrict__ dst, int* __restrict__ indeg,
                           int* __restrict__ rank, int e) {
  int i = blockIdx.x * blockDim.x + threadIdx.x;
  if (i < e) rank[i] = atomicAdd(&indeg[dst[i]], 1);
}

__device__ __forceinline__ int wave_incl_scan(int v, int lane) {
#pragma unroll
  for (int off = 1; off < 64; off <<= 1) {
    int t = __shfl_up(v, off, 64);
    if (lane >= off) v += t;
  }
  return v;
}

// Phase A: bsum[b] = sum of indeg[b*1024 .. b*1024+1024)
__global__ __launch_bounds__(1024) void scan_a_k(const int* __restrict__ indeg,
                                                 int* __restrict__ bsum, int n) {
  const int tid = threadIdx.x;
  const int i = blockIdx.x * 1024 + tid;
  int v = (i < n) ? indeg[i] : 0;
#pragma unroll
  for (int off = 32; off; off >>= 1) v += __shfl_down(v, off, 64);
  __shared__ int ws[16];
  if ((tid & 63) == 0) ws[tid >> 6] = v;
  __syncthreads();
  if (tid < 16) {
    int s = ws[tid];
#pragma unroll
    for (int off = 8; off; off >>= 1) s += __shfl_down(s, off, 16);
    if (tid == 0) bsum[blockIdx.x] = s;
  }
}

// Phase B: exclusive scan of bsum[0..nb) -> bbase; offsets[n] = grand total. nb <= 1024.
__global__ __launch_bounds__(1024) void scan_b_k(const int* __restrict__ bsum,
                                                 int* __restrict__ bbase,
                                                 int* __restrict__ offsets, int nb, int n) {
  __shared__ int ws[16];
  const int tid = threadIdx.x, lane = tid & 63, w = tid >> 6;
  const int v = (tid < nb) ? bsum[tid] : 0;
  int incl = wave_incl_scan(v, lane);
  if (lane == 63) ws[w] = incl;
  __syncthreads();
  if (tid < 16) {
    int s = ws[tid];
#pragma unroll
    for (int off = 1; off < 16; off <<= 1) {
      int t = __shfl_up(s, off, 16);
      if (tid >= off) s += t;
    }
    ws[tid] = s;
  }
  __syncthreads();
  incl += (w > 0 ? ws[w - 1] : 0);
  if (tid < nb) bbase[tid] = incl - v;
  if (tid == 0) offsets[n] = ws[15];
}

// Phase C: per-chunk rescan + base add; also dis = rsqrt(1+indeg)
__global__ __launch_bounds__(1024) void scan_c_k(const int* __restrict__ indeg,
                                                 const int* __restrict__ bbase,
                                                 int* __restrict__ offsets,
                                                 float* __restrict__ dis, int n) {
  __shared__ int ws[16];
  const int tid = threadIdx.x, lane = tid & 63, w = tid >> 6;
  const int i = blockIdx.x * 1024 + tid;
  const int v = (i < n) ? indeg[i] : 0;
  int incl = wave_incl_scan(v, lane);
  if (lane == 63) ws[w] = incl;
  __syncthreads();
  if (tid < 16) {
    int s = ws[tid];
#pragma unroll
    for (int off = 1; off < 16; off <<= 1) {
      int t = __shfl_up(s, off, 16);
      if (tid >= off) s += t;
    }
    ws[tid] = s;
  }
  __syncthreads();
  incl += (w > 0 ? ws[w - 1] : 0);
  if (i < n) {
    offsets[i] = bbase[blockIdx.x] + incl - v;
    dis[i] = rsqrtf((float)(1 + v));
  }
}

// atomic-free slot calc; fire-and-forget atomicExch avoids partial-line store amplification
__global__ void place_k(const int* __restrict__ src, const int* __restrict__ dst,
                        const int* __restrict__ rank, const int* __restrict__ offsets,
                        int* __restrict__ csr_src, int e) {
  int i = blockIdx.x * blockDim.x + threadIdx.x;
  if (i >= e) return;
  int d = dst[i];
  atomicExch(&csr_src[offsets[d] + rank[i]], src[i]);
}

// o[i,:] = dis[i] * x[i,:]
__global__ void scale_k(const float* __restrict__ x, const float* __restrict__ dis,
                        float* __restrict__ o, int n) {
  int t = blockIdx.x * blockDim.x + threadIdx.x;
  if (t >= n * 24) return;
  const float d = dis[t / 24];
  float4 v = ((const float4*)x)[t];
  v.x *= d; v.y *= d; v.z *= d; v.w *= d;
  ((float4*)o)[t] = v;
}

// agg[d,:] = dis[d] * ( hp[d,:] + sum_{s->d} hp[s,:] )   (hp is pre-scaled dis*h)
__global__ __launch_bounds__(192) void gather_k(
    const int* __restrict__ csr_src, const int* __restrict__ offsets,
    const float* __restrict__ dis, const float* __restrict__ hp,
    float* __restrict__ agg, int n) {
  const int tid  = threadIdx.x;
  const int node = blockIdx.x * 8 + tid / 24;
  const int q    = tid % 24;
  if (node >= n) return;
  float4 acc = ((const float4*)(hp + (size_t)node * HDIM))[q];   // self term
  int i = offsets[node];
  const int end = offsets[node + 1];
  for (; i + 3 < end; i += 4) {
    const int s0 = csr_src[i], s1 = csr_src[i + 1], s2 = csr_src[i + 2], s3 = csr_src[i + 3];
    const float4 v0 = ((const float4*)(hp + (size_t)s0 * HDIM))[q];
    const float4 v1 = ((const float4*)(hp + (size_t)s1 * HDIM))[q];
    const float4 v2 = ((const float4*)(hp + (size_t)s2 * HDIM))[q];
    const float4 v3 = ((const float4*)(hp + (size_t)s3 * HDIM))[q];
    acc.x += v0.x + v1.x + v2.x + v3.x;
    acc.y += v0.y + v1.y + v2.y + v3.y;
    acc.z += v0.z + v1.z + v2.z + v3.z;
    acc.w += v0.w + v1.w + v2.w + v3.w;
  }
  for (; i < end; i++) {
    const int s0 = csr_src[i];
    const float4 v0 = ((const float4*)(hp + (size_t)s0 * HDIM))[q];
    acc.x += v0.x; acc.y += v0.y; acc.z += v0.z; acc.w += v0.w;
  }
  const float dd = dis[node];
  acc.x *= dd; acc.y *= dd; acc.z *= dd; acc.w *= dd;
  ((float4*)(agg + (size_t)node * HDIM))[q] = acc;
}

// ---- LDS-resident, K-chunked fp32 GEMM ----
// out[n,96] = [A0|A1][n, 96*nkt] @ W[96*nkt, 96] + bias.
// 64-row x 96-col tile, 384 threads (6 waves), 4x4 micro-tile.
// K processed in 48-row chunks: AsT (13.1 KB, transposed, pad to 68) +
// Ws[DUAL?2:1] (18.4 KB each) -> 31.5/49.9 KB LDS -> 3+ blocks/CU; grid 782
// blocks -> ~18 waves/CU. Inner loop: LDS-only operands (A-read is a
// 3-address broadcast ~1cyc, W-read 96 words = 3 bank-cyc) vs 32/64 FMA cyc.
// DUAL: second weight set reuses staged A; out1 = dis[r]*relu(z1).
template<bool RELU, bool DUAL>
__global__ __launch_bounds__(384) void gemm_k(
    const float* __restrict__ A0, const float* __restrict__ A1,
    const float* __restrict__ W0, const float* __restrict__ b0, float* __restrict__ out0,
    const float* __restrict__ W1, const float* __restrict__ b1, float* __restrict__ out1,
    const float* __restrict__ dis, int n, int nkt) {
  __shared__ float AsT[48 * 68];                  // 13.1 KB
  __shared__ float Ws[DUAL ? 2 : 1][48 * 96];     // 18.4 / 36.9 KB
  const int t  = threadIdx.x;
  const int cg = t % 24;                   // cols [4cg, 4cg+4)
  const int rg = t / 24;                   // rows [4rg, 4rg+4), 16 row-groups
  const int row0 = blockIdx.x * 64;

  float acc0[4][4], acc1[4][4];
  {
    const float4 b = *(const float4*)(b0 + cg * 4);
#pragma unroll
    for (int j = 0; j < 4; j++) { acc0[j][0]=b.x; acc0[j][1]=b.y; acc0[j][2]=b.z; acc0[j][3]=b.w; }
    if (DUAL) {
      const float4 c = *(const float4*)(b1 + cg * 4);
#pragma unroll
      for (int j = 0; j < 4; j++) { acc1[j][0]=c.x; acc1[j][1]=c.y; acc1[j][2]=c.z; acc1[j][3]=c.w; }
    }
  }

  for (int kt = 0; kt < nkt; kt++) {
    const float* A = (kt == 0) ? A0 : A1;
    for (int c0 = 0; c0 < HDIM; c0 += 48) {
      __syncthreads();   // previous chunk fully consumed
      // stage A chunk (64 rows x 48 k) transposed; lanes walk r fastest -> conflict-free
      for (int idx = t; idx < 768; idx += 384) {
        const int q = idx >> 6, r = idx & 63;   // q: k-quad 0..11
        float4 v = make_float4(0.f, 0.f, 0.f, 0.f);
        if (row0 + r < n) v = *(const float4*)(A + (size_t)(row0 + r) * HDIM + c0 + 4 * q);
        AsT[(4 * q + 0) * 68 + r] = v.x;
        AsT[(4 * q + 1) * 68 + r] = v.y;
        AsT[(4 * q + 2) * 68 + r] = v.z;
        AsT[(4 * q + 3) * 68 + r] = v.w;
      }
      // stage W chunk(s): rows [kt*96+c0, +48) x 96 cols, contiguous flat copy
      {
        const float4* wsrc0 = (const float4*)(W0 + ((size_t)kt * HDIM + c0) * HDIM);
        for (int idx = t; idx < 1152; idx += 384) ((float4*)Ws[0])[idx] = wsrc0[idx];
        if (DUAL) {
          const float4* wsrc1 = (const float4*)(W1 + ((size_t)kt * HDIM + c0) * HDIM);
          for (int idx = t; idx < 1152; idx += 384) ((float4*)Ws[1])[idx] = wsrc1[idx];
        }
      }
      __syncthreads();
#pragma unroll 4
      for (int k = 0; k < 48; k++) {
        const float4 a = *(const float4*)(&AsT[k * 68 + rg * 4]);
        const float av[4] = {a.x, a.y, a.z, a.w};
        const float4 w = *(const float4*)(&Ws[0][k * HDIM + cg * 4]);
        const float wv[4] = {w.x, w.y, w.z, w.w};
#pragma unroll
        for (int j = 0; j < 4; j++)
#pragma unroll
          for (int c = 0; c < 4; c++)
            acc0[j][c] = fmaf(av[j], wv[c], acc0[j][c]);
        if (DUAL) {
          const float4 u = *(const float4*)(&Ws[1][k * HDIM + cg * 4]);
          const float uv[4] = {u.x, u.y, u.z, u.w};
#pragma unroll
          for (int j = 0; j < 4; j++)
#pragma unroll
            for (int c = 0; c < 4; c++)
              acc1[j][c] = fmaf(av[j], uv[c], acc1[j][c]);
        }
      }
    }
  }

#pragma unroll
  for (int j = 0; j < 4; j++) {
    const int r = row0 + rg * 4 + j;
    if (r < n) {
      float4 o;
      o.x = RELU ? fmaxf(acc0[j][0], 0.f) : acc0[j][0];
      o.y = RELU ? fmaxf(acc0[j][1], 0.f) : acc0[j][1];
      o.z = RELU ? fmaxf(acc0[j][2], 0.f) : acc0[j][2];
      o.w = RELU ? fmaxf(acc0[j][3], 0.f) : acc0[j][3];
      *(float4*)(out0 + (size_t)r * HDIM + cg * 4) = o;
      if (DUAL) {
        const float d = dis[r];
        float4 p;
        p.x = d * fmaxf(acc1[j][0], 0.f);
        p.y = d * fmaxf(acc1[j][1], 0.f);
        p.z = d * fmaxf(acc1[j][2], 0.f);
        p.w = d * fmaxf(acc1[j][3], 0.f);
        *(float4*)(out1 + (size_t)r * HDIM + cg * 4) = p;
      }
    }
  }
}

extern "C" void kernel_launch(void* const* d_in, const int* in_sizes, int n_in,
                              void* d_out, int out_size, void* d_ws, size_t ws_size,
                              hipStream_t stream) {
  const float* x       = (const float*)d_in[0];
  const int*   edge    = (const int*)d_in[1];
  const float* W_local = (const float*)d_in[2];
  const float* b_local = (const float*)d_in[3];
  const float* W_g1    = (const float*)d_in[4];
  const float* b_g1    = (const float*)d_in[5];
  const float* W_g2    = (const float*)d_in[6];
  const float* b_g2    = (const float*)d_in[7];
  const float* W_fuse  = (const float*)d_in[8]; // [192, 96] row-major
  const float* b_fuse  = (const float*)d_in[9];
  float* out = (float*)d_out;

  const int n = in_sizes[0] / HDIM;
  const int e = in_sizes[1] / 2;
  const int* src = edge;
  const int* dst = edge + e;
  const int nb = (n + 1023) / 1024;

  char* ws = (char*)d_ws;
  auto alloc = [&](size_t bytes) { char* p = ws; ws += (bytes + 255) & ~(size_t)255; return p; };
  int*   indeg   = (int*)alloc((size_t)n * 4);
  float* dis     = (float*)alloc((size_t)n * 4);
  int*   offsets = (int*)alloc((size_t)(n + 1) * 4);
  int*   bsum    = (int*)alloc((size_t)nb * 4);
  int*   bbase   = (int*)alloc((size_t)nb * 4);
  int*   rank    = (int*)alloc((size_t)e * 4);
  int*   csr_src = (int*)alloc((size_t)e * 4);
  float* bufA    = (float*)alloc((size_t)n * HDIM * 4);   // ax / ag2
  float* bufB    = (float*)alloc((size_t)n * HDIM * 4);   // x' then local
  float* bufC    = (float*)alloc((size_t)n * HDIM * 4);   // g1' then g2

  zero_k<<<(n + 255) / 256, 256, 0, stream>>>(indeg, n);
  deg_rank_k<<<(e + 255) / 256, 256, 0, stream>>>(dst, indeg, rank, e);
  scan_a_k<<<nb, 1024, 0, stream>>>(indeg, bsum, n);
  scan_b_k<<<1, 1024, 0, stream>>>(bsum, bbase, offsets, nb, n);
  scan_c_k<<<nb, 1024, 0, stream>>>(indeg, bbase, offsets, dis, n);
  place_k<<<(e + 255) / 256, 256, 0, stream>>>(src, dst, rank, offsets, csr_src, e);

  const int ggrid = (n + 7) / 8;
  const int gb = (n + 63) / 64;

  // x' = dis·x  (bufB is free until the dual GEMM overwrites it)
  scale_k<<<(n * 24 + 255) / 256, 256, 0, stream>>>(x, dis, bufB, n);
  // ax = dis·(x'[d] + Σ x'[s])
  gather_k<<<ggrid, 192, 0, stream>>>(csr_src, offsets, dis, bufB, bufA, n);
  // local = relu(ax@W_local+b);  g1' = dis·relu(ax@W_g1+b)   (one A pass)
  gemm_k<true, true><<<gb, 384, 0, stream>>>(bufA, nullptr, W_local, b_local, bufB,
                                             W_g1, b_g1, bufC, dis, n, 1);
  // ag2 = dis·(g1'[d] + Σ g1'[s]);  g2 = relu(ag2@W_g2+b)
  gather_k<<<ggrid, 192, 0, stream>>>(csr_src, offsets, dis, bufC, bufA, n);
  gemm_k<true, false><<<gb, 384, 0, stream>>>(bufA, nullptr, W_g2, b_g2, bufC,
                                              nullptr, nullptr, nullptr, nullptr, n, 1);
  // out = [local | g2] @ W_fuse + b_fuse   (K=192: two 96-tiles)
  gemm_k<false, false><<<gb, 384, 0, stream>>>(bufB, bufC, W_fuse, b_fuse, out,
                                               nullptr, nullptr, nullptr, nullptr, n, 2);
}